// Round 2
// baseline (7214.184 us; speedup 1.0000x reference)
//
#include <hip/hip_runtime.h>
#include <hip/hip_cooperative_groups.h>
#include <math.h>

#define Q 2048
#define NOBS 8192
#define NSTEPS 32
#define NBLK 256   // cooperative grid size (1 block/CU)

namespace cg = cooperative_groups;

// ---------------------------------------------------------------------------
// block-wide sum, blockDim.x == 256 (4 waves of 64)
__device__ __forceinline__ float block_sum256(float v, volatile float* red) {
  int tid = threadIdx.x;
#pragma unroll
  for (int o = 32; o > 0; o >>= 1) v += __shfl_down(v, o);
  __syncthreads();
  if ((tid & 63) == 0) red[tid >> 6] = v;
  __syncthreads();
  return red[0] + red[1] + red[2] + red[3];
}

// ---------------------------------------------------------------------------
__global__ __launch_bounds__(256) void obs_kernel(
    const float* __restrict__ yt, const float* __restrict__ yp,
    const int* __restrict__ zidx, const float* __restrict__ s2e_p,
    const float* __restrict__ s2b_p, float* __restrict__ t,
    int* __restrict__ cnt, float* __restrict__ scal) {
  __shared__ float red[4];
  int i = blockIdx.x * 256 + threadIdx.x;
  float s2e = s2e_p[0], s2b = s2b_p[0];
  float sig2 = s2e + s2b;
  float r = yt[i] - yp[i];
  float e = erff(r * rsqrtf(2.0f * sig2));
  float u = 0.5f * (e + 1.0f);
  u = fminf(fmaxf(u, 1e-5f), 1.0f - 1e-5f);
  float m = erfinvf(2.0f * u - 1.0f) * 1.4142135623730951f;
  float slp = -0.5f * logf(2.0f * 3.14159265358979f * sig2) - r * r / (2.0f * sig2);
  int z = zidx[i];
  atomicAdd(&t[z], m);
  atomicAdd(&cnt[z], 1);
  float s1 = block_sum256(slp, red);
  float s2 = block_sum256(m * m, red);
  if (threadIdx.x == 0) {
    atomicAdd(&scal[0], s1);   // sum_log_pdf
    atomicAdd(&scal[1], s2);   // m'm
  }
}

// ---------------------------------------------------------------------------
// G[j,k] = sqrt(n_j n_k) * (s2b/sig2) * exp(-dist/(2*ell)) + (s2e/sig2)*delta
__global__ __launch_bounds__(256) void build_G(
    const float* __restrict__ dist, const float* __restrict__ s2e_p,
    const float* __restrict__ s2b_p, const float* __restrict__ ell_p,
    const int* __restrict__ cnt, float* __restrict__ G) {
  int idx = blockIdx.x * 256 + threadIdx.x;
  int j = idx >> 11;
  int k = idx & (Q - 1);
  float s2e = s2e_p[0], s2b = s2b_p[0], ell = ell_p[0];
  float sig2 = s2e + s2b;
  float a = (s2b / sig2) * expf(-dist[idx] / (2.0f * ell));
  float g = sqrtf((float)cnt[j] * (float)cnt[k]) * a;
  if (j == k) g += s2e / sig2;
  G[idx] = g;
}

// ---------------------------------------------------------------------------
// w = A t, b = sqrt(n).*w stored into z-row, tw += t.w
__global__ __launch_bounds__(256) void matvec_kernel(
    const float* __restrict__ dist, const float* __restrict__ s2e_p,
    const float* __restrict__ s2b_p, const float* __restrict__ ell_p,
    const int* __restrict__ cnt, const float* __restrict__ t,
    float* __restrict__ z, float* __restrict__ scal) {
  __shared__ float red[4];
  int j = blockIdx.x;
  float s2e = s2e_p[0], s2b = s2b_p[0], ell = ell_p[0];
  float sig2 = s2e + s2b;
  float inv2ell = 1.0f / (2.0f * ell);
  float s = 0.0f;
  const float* drow = dist + (size_t)j * Q;
  for (int k = threadIdx.x; k < Q; k += 256) s += expf(-drow[k] * inv2ell) * t[k];
  float tot = block_sum256(s, red);
  if (threadIdx.x == 0) {
    float wj = (s2b / sig2) * tot;
    z[j] = sqrtf((float)cnt[j]) * wj;   // b = W^{1/2} w
    atomicAdd(&scal[2], t[j] * wj);     // t.w
  }
}

// ---------------------------------------------------------------------------
// Cooperative Cholesky of G (lower), with RHS z carried as a virtual row Q.
// Per step s:  [wave-0 factors 64x64 diag into LDS; all rows (incl z)
// TRSM-solved] -> grid.sync -> [SYRK trailing update + z trailing update]
// -> grid.sync.  logdet accumulated into scal[3] by block 0.
__global__ __launch_bounds__(256, 1) void chol_coop(
    float* __restrict__ G, float* __restrict__ z, float* __restrict__ scal,
    const float* __restrict__ s2e_p, const float* __restrict__ s2b_p,
    float* __restrict__ out) {
  cg::grid_group grid = cg::this_grid();
  __shared__ __align__(16) float shA[64 * 68];  // Ld (stride 65) / PT (stride 68)
  __shared__ __align__(16) float shB[64 * 68];  // QT (stride 68)
  __shared__ float z1s[64];
  __shared__ float red[256];
  int tid = threadIdx.x;
  int lane = tid & 63, wv = tid >> 6;
  int bx = blockIdx.x;

  for (int s = 0; s < NSTEPS; ++s) {
    int j0 = s * 64;
    int ntr = Q - j0 - 64;     // trailing rows
    int Rtot = ntr + 1;        // + z row

    // ---- phase A: factor diag tile (wave 0, redundant per block) ----
    if (wv == 0) {
      const float* row = G + (size_t)(j0 + lane) * Q + j0;
      float rr[64];
#pragma unroll
      for (int k4 = 0; k4 < 16; ++k4) {
        float4 v = *(const float4*)(row + k4 * 4);
        rr[k4 * 4 + 0] = v.x; rr[k4 * 4 + 1] = v.y;
        rr[k4 * 4 + 2] = v.z; rr[k4 * 4 + 3] = v.w;
      }
#pragma unroll
      for (int j = 0; j < 64; ++j) {
        float vjj = __shfl(rr[j], j);
        float invd = rsqrtf(vjj);
        float lij = rr[j] * invd;   // lane j gets sqrt(vjj)
        rr[j] = lij;
#pragma unroll
        for (int k = 0; k < 64; ++k)
          if (k > j) rr[k] -= lij * __shfl(lij, k);
      }
      float dv = 1.0f;
#pragma unroll
      for (int k = 0; k < 64; ++k) {
        if (k <= lane) shA[lane * 65 + k] = rr[k];
        if (k == lane) dv = rr[k];
      }
      if (bx == 0) {
        float lg = logf(dv);
#pragma unroll
        for (int o = 32; o > 0; o >>= 1) lg += __shfl_down(lg, o);
        if (lane == 0) atomicAdd(&scal[3], lg);
      }
    }
    __syncthreads();

    // ---- phase B: TRSM rows j0+64..Q-1 plus the z row ----
    {
      float dinv = 1.0f / shA[lane * 65 + lane];
      int gw = bx * 4 + wv;                    // 0..1023 global wave id
      for (int ri = gw; ri < Rtot; ri += NBLK * 4) {
        int r = j0 + 64 + ri;
        float* grow = (r < Q) ? (G + (size_t)r * Q + j0) : (z + j0);
        float a = grow[lane];
        for (int p = 0; p < 64; ++p) {
          float xp = __shfl(a, p) * __shfl(dinv, p);
          if (lane > p) a -= xp * shA[lane * 65 + p];
        }
        grow[lane] = a * dinv;
      }
    }
    grid.sync();

    // ---- phase C: SYRK trailing tiles (lower) + z trailing update ----
    int nb = ntr >> 6;
    int ntri = nb * (nb + 1) / 2;
    int njobs = ntri + nb;
    for (int job = bx; job < njobs; job += NBLK) {
      __syncthreads();   // protect LDS reuse across sequential jobs
      if (job < ntri) {
        int bi = (int)((sqrtf(8.0f * (float)job + 1.0f) - 1.0f) * 0.5f);
        while ((bi + 1) * (bi + 2) / 2 <= job) ++bi;
        while (bi * (bi + 1) / 2 > job) --bi;
        int bk = job - bi * (bi + 1) / 2;
        int R0 = j0 + 64 + bi * 64, C0 = j0 + 64 + bk * 64;
        // load both tiles transposed into LDS (stride 68, 16B-aligned rows)
        for (int it = 0; it < 4; ++it) {
          int idx = it * 256 + tid;           // 1024 float4 chunks
          int r = idx >> 4, c4 = (idx & 15) * 4;
          float4 v = *(const float4*)(G + (size_t)(R0 + r) * Q + j0 + c4);
          shA[(c4 + 0) * 68 + r] = v.x; shA[(c4 + 1) * 68 + r] = v.y;
          shA[(c4 + 2) * 68 + r] = v.z; shA[(c4 + 3) * 68 + r] = v.w;
          float4 u = *(const float4*)(G + (size_t)(C0 + r) * Q + j0 + c4);
          shB[(c4 + 0) * 68 + r] = u.x; shB[(c4 + 1) * 68 + r] = u.y;
          shB[(c4 + 2) * 68 + r] = u.z; shB[(c4 + 3) * 68 + r] = u.w;
        }
        __syncthreads();
        int tx = tid & 15, ty = tid >> 4;
        float acc[4][4] = {{0.f}};
        for (int p = 0; p < 64; ++p) {
          float4 a4 = *(const float4*)&shA[p * 68 + ty * 4];
          float4 b4 = *(const float4*)&shB[p * 68 + tx * 4];
          float av[4] = {a4.x, a4.y, a4.z, a4.w};
          float bv[4] = {b4.x, b4.y, b4.z, b4.w};
#pragma unroll
          for (int i = 0; i < 4; ++i)
#pragma unroll
            for (int jj = 0; jj < 4; ++jj) acc[i][jj] += av[i] * bv[jj];
        }
#pragma unroll
        for (int i = 0; i < 4; ++i) {
          float* gp = G + (size_t)(R0 + ty * 4 + i) * Q + C0 + tx * 4;
          float4 g = *(float4*)gp;
          g.x -= acc[i][0]; g.y -= acc[i][1];
          g.z -= acc[i][2]; g.w -= acc[i][3];
          *(float4*)gp = g;
        }
      } else {
        // z trailing update for tile bk: z[C0..C0+63] -= L21_tile . z1
        int bk = job - ntri;
        int C0 = j0 + 64 + bk * 64;
        if (tid < 64) z1s[tid] = z[j0 + tid];
        __syncthreads();
        int rw = tid >> 2, part = tid & 3;
        const float* Lr = G + (size_t)(C0 + rw) * Q + j0;
        float ssum = 0.f;
        for (int p = part; p < 64; p += 4) ssum += Lr[p] * z1s[p];
        ssum += __shfl_down(ssum, 2);
        ssum += __shfl_down(ssum, 1);
        if (part == 0) z[C0 + rw] -= ssum;
      }
    }
    grid.sync();
  }

  // ---- final assembly (block 0) ----
  if (bx == 0) {
    float bv = 0.f;
    for (int i = tid; i < Q; i += 256) { float zi = z[i]; bv += zi * zi; }
    float bvs = block_sum256(bv, red);
    if (tid == 0) {
      float s2e = s2e_p[0], s2b = s2b_p[0];
      float sig2 = s2e + s2b;
      float c = s2e / sig2;
      float slp = scal[0], mtm = scal[1], tw = scal[2], sl = scal[3];
      float tty = (tw - bvs) / c;          // t' y
      float mrm = (mtm - tty) / c;         // m' R^{-1} m
      float logdetR = (float)(NOBS - Q) * logf(c) + 2.0f * sl;
      out[0] = 0.5f * logdetR + 0.5f * mrm - 0.5f * mtm + 0.5f * slp;
    }
  }
}

// ---------------------------------------------------------------------------
extern "C" void kernel_launch(void* const* d_in, const int* in_sizes, int n_in,
                              void* d_out, int out_size, void* d_ws, size_t ws_size,
                              hipStream_t stream) {
  const float* yt   = (const float*)d_in[0];
  const float* yp   = (const float*)d_in[1];
  const int*   zidx = (const int*)d_in[2];
  const float* dist = (const float*)d_in[3];
  const float* s2e  = (const float*)d_in[4];
  const float* s2b  = (const float*)d_in[5];
  const float* ell  = (const float*)d_in[6];

  float* ws   = (float*)d_ws;
  float* G    = ws;                        // Q*Q floats = 16 MB
  float* z    = ws + (size_t)Q * Q;        // Q (RHS b -> solution L^{-1} b)
  float* t    = z + Q;                     // Q
  int*   cnt  = (int*)(t + Q);             // Q
  float* scal = t + 2 * Q;                 // 8: slp, mtm, tw, sumlogL

  hipMemsetAsync(t, 0, (2 * Q + 8) * sizeof(float), stream);

  obs_kernel<<<NOBS / 256, 256, 0, stream>>>(yt, yp, zidx, s2e, s2b, t, cnt, scal);
  build_G<<<(Q * Q) / 256, 256, 0, stream>>>(dist, s2e, s2b, ell, cnt, G);
  matvec_kernel<<<Q, 256, 0, stream>>>(dist, s2e, s2b, ell, cnt, t, z, scal);

  float* outp = (float*)d_out;
  void* args[] = {&G, &z, &scal, (void*)&s2e, (void*)&s2b, &outp};
  hipLaunchCooperativeKernel((const void*)chol_coop, dim3(NBLK), dim3(256),
                             args, 0, stream);
}